// Round 3
// baseline (341.225 us; speedup 1.0000x reference)
//
#include <hip/hip_runtime.h>
#include <math.h>

#define HDIM 256
#define KDIM 16
#define SDIM 200
#define BDIM 512
#define NROWS (BDIM * SDIM)   // 102400
#define TM 64                 // rows per block in kernel 1

typedef __bf16 bf16x8 __attribute__((ext_vector_type(8)));
typedef __bf16 bf16x4 __attribute__((ext_vector_type(4)));
typedef float  f32x4  __attribute__((ext_vector_type(4)));

// ---------------------------------------------------------------------------
// Pack W (K x N, row-major) into fragment-ready split-bf16 layout:
//   dst[((k>>3)*N + n)*8 + (k&7)] = hi/lo bf16 of W[k*N + n]
// so a lane's B-fragment (8 consecutive k at fixed n) is one 16B load.
// ---------------------------------------------------------------------------
__global__ __launch_bounds__(256) void pack_w_kernel(
    const float* __restrict__ src, __bf16* __restrict__ hi,
    __bf16* __restrict__ lo, int lgN)
{
    int idx = blockIdx.x * 256 + threadIdx.x;
    int N = 1 << lgN;
    int k = idx >> lgN;
    int n = idx & (N - 1);
    float v = src[idx];
    __bf16 h = (__bf16)v;
    float r = v - (float)h;
    int d = (((k >> 3) << lgN) + n) * 8 + (k & 7);
    hi[d] = h;
    lo[d] = (__bf16)r;
}

// ---------------------------------------------------------------------------
// Kernel 1: 64-row tile, split-bf16 3-pass MFMA, register double-buffered:
// A-frags (LDS) and B-frags (global/L2) for kc+1 are prefetched before the
// MFMAs of kc, so MFMAs only wait on loads issued one iteration ago.
// ---------------------------------------------------------------------------
__global__ __launch_bounds__(256, 2) void mlp_softk_mfma(
    const float* __restrict__ X, const int* __restrict__ mask,
    const __bf16* __restrict__ W1h, const __bf16* __restrict__ W1l,
    const float* __restrict__ b1,
    const __bf16* __restrict__ W2h, const __bf16* __restrict__ W2l,
    const float* __restrict__ b2,
    const __bf16* __restrict__ W3h, const __bf16* __restrict__ W3l,
    float* __restrict__ P)
{
    __shared__ __bf16 Ahi[TM * HDIM];   // 32 KB
    __shared__ __bf16 Alo[TM * HDIM];   // 32 KB

    const int tid  = threadIdx.x;
    const int lane = tid & 63;
    const int w    = tid >> 6;      // wave id: owns cols 64w..64w+63
    const int l15  = lane & 15;
    const int quad = lane >> 4;
    const long r0  = (long)blockIdx.x * TM;

    // ---- stage X tile -> LDS as split bf16 (swizzled) ----
    {
        const float4* Xt = (const float4*)(X + r0 * HDIM);
        #pragma unroll
        for (int t = 0; t < (TM * HDIM / 4) / 256; ++t) {
            int v4  = tid + t * 256;
            float4 f = Xt[v4];
            int row = v4 >> 6;            // 64 float4 per row
            int col = (v4 & 63) << 2;
            int kgs = (col >> 3) ^ (row & 31);
            int base = row * HDIM + kgs * 8 + (col & 7);
            __bf16 h0 = (__bf16)f.x, h1 = (__bf16)f.y,
                   h2 = (__bf16)f.z, h3 = (__bf16)f.w;
            bf16x4 hv = {h0, h1, h2, h3};
            bf16x4 lv = {(__bf16)(f.x - (float)h0), (__bf16)(f.y - (float)h1),
                         (__bf16)(f.z - (float)h2), (__bf16)(f.w - (float)h3)};
            *(bf16x4*)(&Ahi[base]) = hv;
            *(bf16x4*)(&Alo[base]) = lv;
        }
    }
    __syncthreads();

    f32x4 acc[4][4];

    auto layer = [&](const __bf16* __restrict__ Wh, const __bf16* __restrict__ Wl,
                     const float* __restrict__ bias) {
        #pragma unroll
        for (int mt = 0; mt < 4; ++mt)
            #pragma unroll
            for (int nt = 0; nt < 4; ++nt)
                acc[mt][nt] = (f32x4){0.f, 0.f, 0.f, 0.f};

        bf16x8 ahb[2][4], alb[2][4], bhb[2][4], blb[2][4];

        auto loadB = [&](int kc, int s) {
            #pragma unroll
            for (int nt = 0; nt < 4; ++nt) {
                int n  = w * 64 + nt * 16 + l15;
                int kg = kc * 4 + quad;
                bhb[s][nt] = *(const bf16x8*)(Wh + (kg * HDIM + n) * 8);
                blb[s][nt] = *(const bf16x8*)(Wl + (kg * HDIM + n) * 8);
            }
        };
        auto loadA = [&](int kc, int s) {
            #pragma unroll
            for (int mt = 0; mt < 4; ++mt) {
                int row = mt * 16 + l15;
                int kgs = (kc * 4 + quad) ^ (row & 31);
                ahb[s][mt] = *(const bf16x8*)(&Ahi[row * HDIM + kgs * 8]);
                alb[s][mt] = *(const bf16x8*)(&Alo[row * HDIM + kgs * 8]);
            }
        };

        loadB(0, 0);
        loadA(0, 0);

        #pragma unroll
        for (int kc = 0; kc < 8; ++kc) {
            const int cur = kc & 1, nxt = cur ^ 1;
            if (kc < 7) {          // prefetch next k-chunk while computing
                loadB(kc + 1, nxt);
                loadA(kc + 1, nxt);
            }
            #pragma unroll
            for (int mt = 0; mt < 4; ++mt)
                #pragma unroll
                for (int nt = 0; nt < 4; ++nt) {
                    acc[mt][nt] = __builtin_amdgcn_mfma_f32_16x16x32_bf16(
                        ahb[cur][mt], bhb[cur][nt], acc[mt][nt], 0, 0, 0);
                    acc[mt][nt] = __builtin_amdgcn_mfma_f32_16x16x32_bf16(
                        alb[cur][mt], bhb[cur][nt], acc[mt][nt], 0, 0, 0);
                    acc[mt][nt] = __builtin_amdgcn_mfma_f32_16x16x32_bf16(
                        ahb[cur][mt], blb[cur][nt], acc[mt][nt], 0, 0, 0);
                }
        }
        __syncthreads();   // everyone done reading A before overwrite

        float bias_v[4];
        #pragma unroll
        for (int nt = 0; nt < 4; ++nt) bias_v[nt] = bias[w * 64 + nt * 16 + l15];
        #pragma unroll
        for (int mt = 0; mt < 4; ++mt)
            #pragma unroll
            for (int nt = 0; nt < 4; ++nt)
                #pragma unroll
                for (int r = 0; r < 4; ++r) {
                    float v = fmaxf(acc[mt][nt][r] + bias_v[nt], 0.f);
                    int row = mt * 16 + quad * 4 + r;   // C layout: row=(l>>4)*4+reg
                    int col = w * 64 + nt * 16 + l15;   //           col=l&15
                    int idx = row * HDIM + (((col >> 3) ^ (row & 31)) * 8) + (col & 7);
                    __bf16 h = (__bf16)v;
                    Ahi[idx] = h;
                    Alo[idx] = (__bf16)(v - (float)h);
                }
        __syncthreads();
    };

    layer(W1h, W1l, b1);
    layer(W2h, W2l, b2);

    // ---- logits: wave w handles m-tile w (16 rows x 16 k) ----
    f32x4 lg = {0.f, 0.f, 0.f, 0.f};
    #pragma unroll
    for (int kc = 0; kc < 8; ++kc) {
        int row = w * 16 + l15;
        int kg  = kc * 4 + quad;
        int kgs = kg ^ (row & 31);
        bf16x8 ah = *(const bf16x8*)(&Ahi[row * HDIM + kgs * 8]);
        bf16x8 al = *(const bf16x8*)(&Alo[row * HDIM + kgs * 8]);
        bf16x8 bh = *(const bf16x8*)(W3h + (kg * KDIM + l15) * 8);
        bf16x8 bl = *(const bf16x8*)(W3l + (kg * KDIM + l15) * 8);
        lg = __builtin_amdgcn_mfma_f32_16x16x32_bf16(ah, bh, lg, 0, 0, 0);
        lg = __builtin_amdgcn_mfma_f32_16x16x32_bf16(al, bh, lg, 0, 0, 0);
        lg = __builtin_amdgcn_mfma_f32_16x16x32_bf16(ah, bl, lg, 0, 0, 0);
    }

    // ---- softmax over k (16 lanes of a group hold the 16 cols of a row) ----
    #pragma unroll
    for (int r = 0; r < 4; ++r) {
        float v  = lg[r];
        float mx = v;
        mx = fmaxf(mx, __shfl_xor(mx, 1));
        mx = fmaxf(mx, __shfl_xor(mx, 2));
        mx = fmaxf(mx, __shfl_xor(mx, 4));
        mx = fmaxf(mx, __shfl_xor(mx, 8));
        float e = __expf(v - mx);
        float s = e;
        s += __shfl_xor(s, 1);
        s += __shfl_xor(s, 2);
        s += __shfl_xor(s, 4);
        s += __shfl_xor(s, 8);
        int grow = (int)r0 + w * 16 + quad * 4 + r;
        int mv   = mask[grow];
        float ov = mv ? (e / s) * 0.25f : -2500.0f;   // (-10000)/sqrt(16)
        P[(long)grow * KDIM + l15] = ov;
    }
}

// ---------------------------------------------------------------------------
// Kernel 2: per-b softmax over S (no max-sub needed: logits <= 0.25 or -2500,
// exp(-2500)==0 reproduces the mask), * time_f_w, then
//   out[b,k,h] = sum_s X[b,s,h] * D[s,k].
// Wave w owns h-cols 64w..64w+63 (scalar coalesced X loads, read once per
// block) and ALL 16 k in registers; D comes from LDS f32x4 broadcasts (free).
// ---------------------------------------------------------------------------
__global__ __launch_bounds__(256) void softs_agg_kernel(
    const float* __restrict__ X, const float* __restrict__ tf,
    const float* __restrict__ P, float* __restrict__ out)
{
    __shared__ float wl[SDIM * KDIM];   // 12.8 KB
    __shared__ float tfl[SDIM];
    __shared__ float psum[256];
    __shared__ float invk[KDIM];

    const int tid = threadIdx.x;
    const int b   = blockIdx.x;

    const float* Pb = P + (long)b * SDIM * KDIM;
    float ps = 0.f;
    #pragma unroll
    for (int t = 0; t < 13; ++t) {
        int i = tid + t * 256;
        if (i < SDIM * KDIM) {
            float e = __expf(Pb[i]);
            wl[i] = e;
            ps += e;
        }
    }
    psum[tid] = ps;
    if (tid < SDIM) tfl[tid] = tf[b * SDIM + tid];
    __syncthreads();

    if (tid < KDIM) {
        float s = 0.f;
        #pragma unroll
        for (int g = 0; g < 16; ++g) s += psum[tid + g * 16];
        invk[tid] = 1.f / s;
    }
    __syncthreads();

    #pragma unroll
    for (int t = 0; t < 13; ++t) {
        int i = tid + t * 256;
        if (i < SDIM * KDIM) wl[i] *= tfl[i >> 4] * invk[i & 15];
    }
    __syncthreads();

    const int w  = tid >> 6;    // wave -> h-chunk 64w..64w+63
    const int ln = tid & 63;
    float acc[KDIM];
    #pragma unroll
    for (int k = 0; k < KDIM; ++k) acc[k] = 0.f;

    const float* Xb  = X + (long)b * SDIM * HDIM + w * 64 + ln;
    const f32x4* wl4 = (const f32x4*)wl;
    #pragma unroll 4
    for (int s = 0; s < SDIM; ++s) {
        float x = Xb[(long)s * HDIM];          // coalesced 256B per wave
        f32x4 d0 = wl4[s * 4 + 0];             // LDS broadcast (free)
        f32x4 d1 = wl4[s * 4 + 1];
        f32x4 d2 = wl4[s * 4 + 2];
        f32x4 d3 = wl4[s * 4 + 3];
        #pragma unroll
        for (int j = 0; j < 4; ++j) {
            acc[0 + j]  = fmaf(x, d0[j], acc[0 + j]);
            acc[4 + j]  = fmaf(x, d1[j], acc[4 + j]);
            acc[8 + j]  = fmaf(x, d2[j], acc[8 + j]);
            acc[12 + j] = fmaf(x, d3[j], acc[12 + j]);
        }
    }

    float* ob = out + (long)b * KDIM * HDIM + w * 64 + ln;
    #pragma unroll
    for (int k = 0; k < KDIM; ++k)
        ob[(long)k * HDIM] = acc[k];
}

extern "C" void kernel_launch(void* const* d_in, const int* in_sizes, int n_in,
                              void* d_out, int out_size, void* d_ws, size_t ws_size,
                              hipStream_t stream) {
    (void)in_sizes; (void)n_in; (void)out_size; (void)ws_size;
    const float* X    = (const float*)d_in[0];
    const int*   mask = (const int*)  d_in[1];
    const float* tf   = (const float*)d_in[2];
    const float* W1   = (const float*)d_in[3];
    const float* b1   = (const float*)d_in[4];
    const float* W2   = (const float*)d_in[5];
    const float* b2   = (const float*)d_in[6];
    const float* W3   = (const float*)d_in[7];
    float* out = (float*)d_out;

    char* ws = (char*)d_ws;
    float*  P   = (float*)ws;                          // 102400*16*4 = 6,553,600 B
    __bf16* w1h = (__bf16*)(ws + 6553600);             // 65536 elems each
    __bf16* w1l = w1h + 65536;
    __bf16* w2h = w1l + 65536;
    __bf16* w2l = w2h + 65536;
    __bf16* w3h = w2l + 65536;                         // 4096 elems each
    __bf16* w3l = w3h + 4096;

    pack_w_kernel<<<256, 256, 0, stream>>>(W1, w1h, w1l, 8);
    pack_w_kernel<<<256, 256, 0, stream>>>(W2, w2h, w2l, 8);
    pack_w_kernel<<<16,  256, 0, stream>>>(W3, w3h, w3l, 4);
    mlp_softk_mfma<<<NROWS / TM, 256, 0, stream>>>(X, mask, w1h, w1l, b1,
                                                   w2h, w2l, b2, w3h, w3l, P);
    softs_agg_kernel<<<BDIM, 256, 0, stream>>>(X, tf, P, out);
}

// Round 4
// 293.274 us; speedup vs baseline: 1.1635x; 1.1635x over previous
//
#include <hip/hip_runtime.h>
#include <math.h>

#define HDIM 256
#define KDIM 16
#define SDIM 200
#define BDIM 512
#define NROWS (BDIM * SDIM)   // 102400
#define TM 64                 // rows per block in kernel 1

typedef __bf16 bf16x8 __attribute__((ext_vector_type(8)));
typedef __bf16 bf16x4 __attribute__((ext_vector_type(4)));
typedef float  f32x4  __attribute__((ext_vector_type(4)));

// ---------------------------------------------------------------------------
// Pack W (K x N, row-major) into fragment-ready split-bf16 layout:
//   dst[((k>>3)*N + n)*8 + (k&7)] = hi/lo bf16 of W[k*N + n]
// ---------------------------------------------------------------------------
__global__ __launch_bounds__(256) void pack_w_kernel(
    const float* __restrict__ src, __bf16* __restrict__ hi,
    __bf16* __restrict__ lo, int lgN)
{
    int idx = blockIdx.x * 256 + threadIdx.x;
    int N = 1 << lgN;
    int k = idx >> lgN;
    int n = idx & (N - 1);
    float v = src[idx];
    __bf16 h = (__bf16)v;
    float r = v - (float)h;
    int d = (((k >> 3) << lgN) + n) * 8 + (k & 7);
    hi[d] = h;
    lo[d] = (__bf16)r;
}

// ---------------------------------------------------------------------------
// Kernel 1: 64-row tile, split-bf16 3-pass MFMA.
// ONLY the global-B frags are register double-buffered (fits the 256-reg
// unified budget at 2 waves/SIMD; full A+B dbuf spilled in round 3).
// Next layer's B(0) is prefetched during each epilogue.
// ---------------------------------------------------------------------------
__global__ __launch_bounds__(256, 2) void mlp_softk_mfma(
    const float* __restrict__ X, const int* __restrict__ mask,
    const __bf16* __restrict__ W1h, const __bf16* __restrict__ W1l,
    const float* __restrict__ b1,
    const __bf16* __restrict__ W2h, const __bf16* __restrict__ W2l,
    const float* __restrict__ b2,
    const __bf16* __restrict__ W3h, const __bf16* __restrict__ W3l,
    float* __restrict__ P)
{
    __shared__ __bf16 Ahi[TM * HDIM];   // 32 KB
    __shared__ __bf16 Alo[TM * HDIM];   // 32 KB

    const int tid  = threadIdx.x;
    const int lane = tid & 63;
    const int w    = tid >> 6;      // wave id: owns cols 64w..64w+63
    const int l15  = lane & 15;
    const int quad = lane >> 4;
    const long r0  = (long)blockIdx.x * TM;

    bf16x8 bhb[2][4], blb[2][4];    // global-B double buffer (64 VGPRs)
    bf16x8 bh2[2], bl2[2];          // W3 logits B double buffer

    auto loadB = [&](const __bf16* __restrict__ Wh,
                     const __bf16* __restrict__ Wl, int kc, int s) {
        #pragma unroll
        for (int nt = 0; nt < 4; ++nt) {
            int n  = w * 64 + nt * 16 + l15;
            int kg = kc * 4 + quad;
            bhb[s][nt] = *(const bf16x8*)(Wh + (kg * HDIM + n) * 8);
            blb[s][nt] = *(const bf16x8*)(Wl + (kg * HDIM + n) * 8);
        }
    };

    loadB(W1h, W1l, 0, 0);          // in flight while we stage X

    // ---- stage X tile -> LDS as split bf16 (swizzled) ----
    {
        const float4* Xt = (const float4*)(X + r0 * HDIM);
        #pragma unroll
        for (int t = 0; t < (TM * HDIM / 4) / 256; ++t) {
            int v4  = tid + t * 256;
            float4 f = Xt[v4];
            int row = v4 >> 6;            // 64 float4 per row
            int col = (v4 & 63) << 2;
            int kgs = (col >> 3) ^ (row & 31);
            int base = row * HDIM + kgs * 8 + (col & 7);
            __bf16 h0 = (__bf16)f.x, h1 = (__bf16)f.y,
                   h2 = (__bf16)f.z, h3 = (__bf16)f.w;
            bf16x4 hv = {h0, h1, h2, h3};
            bf16x4 lv = {(__bf16)(f.x - (float)h0), (__bf16)(f.y - (float)h1),
                         (__bf16)(f.z - (float)h2), (__bf16)(f.w - (float)h3)};
            *(bf16x4*)(&Ahi[base]) = hv;
            *(bf16x4*)(&Alo[base]) = lv;
        }
    }
    __syncthreads();

    f32x4 acc[4][4];

    // layer assumes B(kc=0) already resides in slot 0; leaves next op's B(0)
    // in slot 0 (prefetched during its own epilogue).
    auto layer = [&](const __bf16* __restrict__ Wh, const __bf16* __restrict__ Wl,
                     const float* __restrict__ bias,
                     const __bf16* __restrict__ nWh, const __bf16* __restrict__ nWl,
                     bool next_is_w3) {
        #pragma unroll
        for (int mt = 0; mt < 4; ++mt)
            #pragma unroll
            for (int nt = 0; nt < 4; ++nt)
                acc[mt][nt] = (f32x4){0.f, 0.f, 0.f, 0.f};

        #pragma unroll
        for (int kc = 0; kc < 8; ++kc) {
            const int cur = kc & 1, nxt = cur ^ 1;
            bf16x8 ah[4], al[4];
            #pragma unroll
            for (int mt = 0; mt < 4; ++mt) {
                int row = mt * 16 + l15;
                int kgs = (kc * 4 + quad) ^ (row & 31);
                ah[mt] = *(const bf16x8*)(&Ahi[row * HDIM + kgs * 8]);
                al[mt] = *(const bf16x8*)(&Alo[row * HDIM + kgs * 8]);
            }
            if (kc < 7) loadB(Wh, Wl, kc + 1, nxt);   // hide global latency
            #pragma unroll
            for (int mt = 0; mt < 4; ++mt)
                #pragma unroll
                for (int nt = 0; nt < 4; ++nt) {
                    acc[mt][nt] = __builtin_amdgcn_mfma_f32_16x16x32_bf16(
                        ah[mt], bhb[cur][nt], acc[mt][nt], 0, 0, 0);
                    acc[mt][nt] = __builtin_amdgcn_mfma_f32_16x16x32_bf16(
                        al[mt], bhb[cur][nt], acc[mt][nt], 0, 0, 0);
                    acc[mt][nt] = __builtin_amdgcn_mfma_f32_16x16x32_bf16(
                        ah[mt], blb[cur][nt], acc[mt][nt], 0, 0, 0);
                }
        }

        // Prefetch next operator's first B during the epilogue (slot 0 free).
        if (next_is_w3) {
            bh2[0] = *(const bf16x8*)(W3h + (quad * KDIM + l15) * 8);
            bl2[0] = *(const bf16x8*)(W3l + (quad * KDIM + l15) * 8);
        } else {
            loadB(nWh, nWl, 0, 0);
        }
        __syncthreads();   // everyone done reading A before overwrite

        float bias_v[4];
        #pragma unroll
        for (int nt = 0; nt < 4; ++nt) bias_v[nt] = bias[w * 64 + nt * 16 + l15];
        #pragma unroll
        for (int mt = 0; mt < 4; ++mt)
            #pragma unroll
            for (int nt = 0; nt < 4; ++nt)
                #pragma unroll
                for (int r = 0; r < 4; ++r) {
                    float v = fmaxf(acc[mt][nt][r] + bias_v[nt], 0.f);
                    int row = mt * 16 + quad * 4 + r;   // C layout: row=(l>>4)*4+reg
                    int col = w * 64 + nt * 16 + l15;   //           col=l&15
                    int idx = row * HDIM + (((col >> 3) ^ (row & 31)) * 8) + (col & 7);
                    __bf16 h = (__bf16)v;
                    Ahi[idx] = h;
                    Alo[idx] = (__bf16)(v - (float)h);
                }
        __syncthreads();
    };

    layer(W1h, W1l, b1, W2h, W2l, false);
    layer(W2h, W2l, b2, nullptr, nullptr, true);

    // ---- logits: wave w handles m-tile w (16 rows x 16 k), B double-buffered ----
    f32x4 lg = {0.f, 0.f, 0.f, 0.f};
    #pragma unroll
    for (int kc = 0; kc < 8; ++kc) {
        const int cur = kc & 1, nxt = cur ^ 1;
        if (kc < 7) {
            int kg = (kc + 1) * 4 + quad;
            bh2[nxt] = *(const bf16x8*)(W3h + (kg * KDIM + l15) * 8);
            bl2[nxt] = *(const bf16x8*)(W3l + (kg * KDIM + l15) * 8);
        }
        int row = w * 16 + l15;
        int kg  = kc * 4 + quad;
        int kgs = kg ^ (row & 31);
        bf16x8 ah = *(const bf16x8*)(&Ahi[row * HDIM + kgs * 8]);
        bf16x8 al = *(const bf16x8*)(&Alo[row * HDIM + kgs * 8]);
        lg = __builtin_amdgcn_mfma_f32_16x16x32_bf16(ah, bh2[cur], lg, 0, 0, 0);
        lg = __builtin_amdgcn_mfma_f32_16x16x32_bf16(al, bh2[cur], lg, 0, 0, 0);
        lg = __builtin_amdgcn_mfma_f32_16x16x32_bf16(ah, bl2[cur], lg, 0, 0, 0);
    }

    // ---- softmax over k (16 lanes of a group hold the 16 cols of a row) ----
    #pragma unroll
    for (int r = 0; r < 4; ++r) {
        float v  = lg[r];
        float mx = v;
        mx = fmaxf(mx, __shfl_xor(mx, 1));
        mx = fmaxf(mx, __shfl_xor(mx, 2));
        mx = fmaxf(mx, __shfl_xor(mx, 4));
        mx = fmaxf(mx, __shfl_xor(mx, 8));
        float e = __expf(v - mx);
        float s = e;
        s += __shfl_xor(s, 1);
        s += __shfl_xor(s, 2);
        s += __shfl_xor(s, 4);
        s += __shfl_xor(s, 8);
        int grow = (int)r0 + w * 16 + quad * 4 + r;
        int mv   = mask[grow];
        float ov = mv ? (e / s) * 0.25f : -2500.0f;   // (-10000)/sqrt(16)
        P[(long)grow * KDIM + l15] = ov;
    }
}

// ---------------------------------------------------------------------------
// Kernel 2: grid (b, h-chunk) = 512*4 blocks. Per block: softmax over S of
// P[b] (exp(-2500)==0 reproduces the mask), * time_f_w, then each wave sums
// 50 s-rows for its 64 h-cols, LDS tree-reduce over the 4 waves.
// X is read exactly once across the grid.
// ---------------------------------------------------------------------------
__global__ __launch_bounds__(256) void softs_agg_kernel(
    const float* __restrict__ X, const float* __restrict__ tf,
    const float* __restrict__ P, float* __restrict__ out)
{
    __shared__ float wl[SDIM * KDIM];        // 12.8 KB
    __shared__ float tfl[SDIM];
    __shared__ float psum[256];
    __shared__ float invk[KDIM];
    __shared__ float red[4 * KDIM * 64];     // 16 KB

    const int tid = threadIdx.x;
    const int b   = blockIdx.x >> 2;
    const int hj  = blockIdx.x & 3;          // h-chunk: cols 64*hj..64*hj+63

    const float* Pb = P + (long)b * SDIM * KDIM;
    float ps = 0.f;
    #pragma unroll
    for (int t = 0; t < 13; ++t) {
        int i = tid + t * 256;
        if (i < SDIM * KDIM) {
            float e = __expf(Pb[i]);
            wl[i] = e;
            ps += e;
        }
    }
    psum[tid] = ps;
    if (tid < SDIM) tfl[tid] = tf[b * SDIM + tid];
    __syncthreads();

    if (tid < KDIM) {
        float s = 0.f;
        #pragma unroll
        for (int g = 0; g < 16; ++g) s += psum[tid + g * 16];
        invk[tid] = 1.f / s;
    }
    __syncthreads();

    #pragma unroll
    for (int t = 0; t < 13; ++t) {
        int i = tid + t * 256;
        if (i < SDIM * KDIM) wl[i] *= tfl[i >> 4] * invk[i & 15];
    }
    __syncthreads();

    const int wv = tid >> 6;    // wave -> s-range [50*wv, 50*wv+50)
    const int ln = tid & 63;    // lane -> h-col
    float acc[KDIM];
    #pragma unroll
    for (int k = 0; k < KDIM; ++k) acc[k] = 0.f;

    const float* Xb  = X + (long)b * SDIM * HDIM + hj * 64 + ln;
    const f32x4* wl4 = (const f32x4*)wl;
    const int s0 = wv * 50;
    #pragma unroll 5
    for (int si = 0; si < 50; ++si) {
        int s = s0 + si;
        float x = Xb[(long)s * HDIM];          // coalesced 256B per wave
        f32x4 d0 = wl4[s * 4 + 0];             // LDS broadcast (free)
        f32x4 d1 = wl4[s * 4 + 1];
        f32x4 d2 = wl4[s * 4 + 2];
        f32x4 d3 = wl4[s * 4 + 3];
        #pragma unroll
        for (int j = 0; j < 4; ++j) {
            acc[0 + j]  = fmaf(x, d0[j], acc[0 + j]);
            acc[4 + j]  = fmaf(x, d1[j], acc[4 + j]);
            acc[8 + j]  = fmaf(x, d2[j], acc[8 + j]);
            acc[12 + j] = fmaf(x, d3[j], acc[12 + j]);
        }
    }

    #pragma unroll
    for (int k = 0; k < KDIM; ++k)
        red[(wv * KDIM + k) * 64 + ln] = acc[k];
    __syncthreads();

    #pragma unroll
    for (int t = 0; t < 4; ++t) {
        int idx = tid + t * 256;              // 1024 outputs: 16 k x 64 cols
        int k = idx >> 6, c = idx & 63;
        float v = red[(0 * KDIM + k) * 64 + c] + red[(1 * KDIM + k) * 64 + c] +
                  red[(2 * KDIM + k) * 64 + c] + red[(3 * KDIM + k) * 64 + c];
        out[(long)b * KDIM * HDIM + k * HDIM + hj * 64 + c] = v;
    }
}

extern "C" void kernel_launch(void* const* d_in, const int* in_sizes, int n_in,
                              void* d_out, int out_size, void* d_ws, size_t ws_size,
                              hipStream_t stream) {
    (void)in_sizes; (void)n_in; (void)out_size; (void)ws_size;
    const float* X    = (const float*)d_in[0];
    const int*   mask = (const int*)  d_in[1];
    const float* tf   = (const float*)d_in[2];
    const float* W1   = (const float*)d_in[3];
    const float* b1   = (const float*)d_in[4];
    const float* W2   = (const float*)d_in[5];
    const float* b2   = (const float*)d_in[6];
    const float* W3   = (const float*)d_in[7];
    float* out = (float*)d_out;

    char* ws = (char*)d_ws;
    float*  P   = (float*)ws;                          // 102400*16*4 = 6,553,600 B
    __bf16* w1h = (__bf16*)(ws + 6553600);             // 65536 elems each
    __bf16* w1l = w1h + 65536;
    __bf16* w2h = w1l + 65536;
    __bf16* w2l = w2h + 65536;
    __bf16* w3h = w2l + 65536;                         // 4096 elems each
    __bf16* w3l = w3h + 4096;

    pack_w_kernel<<<256, 256, 0, stream>>>(W1, w1h, w1l, 8);
    pack_w_kernel<<<256, 256, 0, stream>>>(W2, w2h, w2l, 8);
    pack_w_kernel<<<16,  256, 0, stream>>>(W3, w3h, w3l, 4);
    mlp_softk_mfma<<<NROWS / TM, 256, 0, stream>>>(X, mask, w1h, w1l, b1,
                                                   w2h, w2l, b2, w3h, w3l, P);
    softs_agg_kernel<<<BDIM * 4, 256, 0, stream>>>(X, tf, P, out);
}

// Round 5
// 285.214 us; speedup vs baseline: 1.1964x; 1.0283x over previous
//
#include <hip/hip_runtime.h>
#include <math.h>

#define HDIM 256
#define KDIM 16
#define SDIM 200
#define BDIM 512
#define NROWS (BDIM * SDIM)   // 102400
#define TM 32                 // rows per block in kernel 1 (32KB LDS -> 4 blocks/CU)

typedef __bf16 bf16x8 __attribute__((ext_vector_type(8)));
typedef __bf16 bf16x4 __attribute__((ext_vector_type(4)));
typedef float  f32x4  __attribute__((ext_vector_type(4)));

// ---------------------------------------------------------------------------
// Pack W (K x N, row-major) into fragment-ready split-bf16 layout:
//   dst[((k>>3)*N + n)*8 + (k&7)] = hi/lo bf16 of W[k*N + n]
// ---------------------------------------------------------------------------
__global__ __launch_bounds__(256) void pack_w_kernel(
    const float* __restrict__ src, __bf16* __restrict__ hi,
    __bf16* __restrict__ lo, int lgN)
{
    int idx = blockIdx.x * 256 + threadIdx.x;
    int N = 1 << lgN;
    int k = idx >> lgN;
    int n = idx & (N - 1);
    float v = src[idx];
    __bf16 h = (__bf16)v;
    float r = v - (float)h;
    int d = (((k >> 3) << lgN) + n) * 8 + (k & 7);
    hi[d] = h;
    lo[d] = (__bf16)r;
}

// ---------------------------------------------------------------------------
// Kernel 1: 32-row tile, split-bf16 3-pass MFMA. 4 blocks/CU (16 waves) so
// TLP hides barriers/epilogues. No register double-buffer (R2 vs R4 showed
// it's worth nothing and the spill costs 20MB of scratch traffic).
// ---------------------------------------------------------------------------
__global__ __launch_bounds__(256, 4) void mlp_softk_mfma(
    const float* __restrict__ X, const int* __restrict__ mask,
    const __bf16* __restrict__ W1h, const __bf16* __restrict__ W1l,
    const float* __restrict__ b1,
    const __bf16* __restrict__ W2h, const __bf16* __restrict__ W2l,
    const float* __restrict__ b2,
    const __bf16* __restrict__ W3h, const __bf16* __restrict__ W3l,
    float* __restrict__ P)
{
    __shared__ __bf16 Ahi[TM * HDIM];   // 16 KB
    __shared__ __bf16 Alo[TM * HDIM];   // 16 KB

    const int tid  = threadIdx.x;
    const int lane = tid & 63;
    const int w    = tid >> 6;      // wave id: owns cols 64w..64w+63
    const int l15  = lane & 15;
    const int quad = lane >> 4;
    const long r0  = (long)blockIdx.x * TM;

    // ---- stage X tile -> LDS as split bf16 (swizzled) ----
    {
        const float4* Xt = (const float4*)(X + r0 * HDIM);
        #pragma unroll
        for (int t = 0; t < (TM * HDIM / 4) / 256; ++t) {
            int v4  = tid + t * 256;
            float4 f = Xt[v4];
            int row = v4 >> 6;            // 64 float4 per row
            int col = (v4 & 63) << 2;
            int kgs = (col >> 3) ^ (row & 31);
            int base = row * HDIM + kgs * 8 + (col & 7);
            __bf16 h0 = (__bf16)f.x, h1 = (__bf16)f.y,
                   h2 = (__bf16)f.z, h3 = (__bf16)f.w;
            bf16x4 hv = {h0, h1, h2, h3};
            bf16x4 lv = {(__bf16)(f.x - (float)h0), (__bf16)(f.y - (float)h1),
                         (__bf16)(f.z - (float)h2), (__bf16)(f.w - (float)h3)};
            *(bf16x4*)(&Ahi[base]) = hv;
            *(bf16x4*)(&Alo[base]) = lv;
        }
    }
    __syncthreads();

    f32x4 acc[2][4];

    auto layer = [&](const __bf16* __restrict__ Wh, const __bf16* __restrict__ Wl,
                     const float* __restrict__ bias) {
        #pragma unroll
        for (int mt = 0; mt < 2; ++mt)
            #pragma unroll
            for (int nt = 0; nt < 4; ++nt)
                acc[mt][nt] = (f32x4){0.f, 0.f, 0.f, 0.f};

        #pragma unroll 2
        for (int kc = 0; kc < 8; ++kc) {
            bf16x8 bh[4], bl[4], ah[2], al[2];
            #pragma unroll
            for (int nt = 0; nt < 4; ++nt) {
                int n  = w * 64 + nt * 16 + l15;
                int kg = kc * 4 + quad;
                bh[nt] = *(const bf16x8*)(Wh + (kg * HDIM + n) * 8);
                bl[nt] = *(const bf16x8*)(Wl + (kg * HDIM + n) * 8);
            }
            #pragma unroll
            for (int mt = 0; mt < 2; ++mt) {
                int row = mt * 16 + l15;
                int kgs = (kc * 4 + quad) ^ (row & 31);
                ah[mt] = *(const bf16x8*)(&Ahi[row * HDIM + kgs * 8]);
                al[mt] = *(const bf16x8*)(&Alo[row * HDIM + kgs * 8]);
            }
            #pragma unroll
            for (int mt = 0; mt < 2; ++mt)
                #pragma unroll
                for (int nt = 0; nt < 4; ++nt) {
                    acc[mt][nt] = __builtin_amdgcn_mfma_f32_16x16x32_bf16(
                        ah[mt], bh[nt], acc[mt][nt], 0, 0, 0);
                    acc[mt][nt] = __builtin_amdgcn_mfma_f32_16x16x32_bf16(
                        al[mt], bh[nt], acc[mt][nt], 0, 0, 0);
                    acc[mt][nt] = __builtin_amdgcn_mfma_f32_16x16x32_bf16(
                        ah[mt], bl[nt], acc[mt][nt], 0, 0, 0);
                }
        }
        __syncthreads();   // everyone done reading A before overwrite

        float bias_v[4];
        #pragma unroll
        for (int nt = 0; nt < 4; ++nt) bias_v[nt] = bias[w * 64 + nt * 16 + l15];
        #pragma unroll
        for (int mt = 0; mt < 2; ++mt)
            #pragma unroll
            for (int nt = 0; nt < 4; ++nt)
                #pragma unroll
                for (int r = 0; r < 4; ++r) {
                    float v = fmaxf(acc[mt][nt][r] + bias_v[nt], 0.f);
                    int row = mt * 16 + quad * 4 + r;   // C layout: row=(l>>4)*4+reg
                    int col = w * 64 + nt * 16 + l15;   //           col=l&15
                    int idx = row * HDIM + (((col >> 3) ^ (row & 31)) * 8) + (col & 7);
                    __bf16 h = (__bf16)v;
                    Ahi[idx] = h;
                    Alo[idx] = (__bf16)(v - (float)h);
                }
        __syncthreads();
    };

    layer(W1h, W1l, b1);
    layer(W2h, W2l, b2);

    // ---- logits: waves 0,1 each handle one 16-row m-tile (TM=32) ----
    if (w < 2) {
        f32x4 lg = {0.f, 0.f, 0.f, 0.f};
        #pragma unroll
        for (int kc = 0; kc < 8; ++kc) {
            int row = w * 16 + l15;
            int kg  = kc * 4 + quad;
            int kgs = kg ^ (row & 31);
            bf16x8 ah = *(const bf16x8*)(&Ahi[row * HDIM + kgs * 8]);
            bf16x8 al = *(const bf16x8*)(&Alo[row * HDIM + kgs * 8]);
            bf16x8 bh = *(const bf16x8*)(W3h + (kg * KDIM + l15) * 8);
            bf16x8 bl = *(const bf16x8*)(W3l + (kg * KDIM + l15) * 8);
            lg = __builtin_amdgcn_mfma_f32_16x16x32_bf16(ah, bh, lg, 0, 0, 0);
            lg = __builtin_amdgcn_mfma_f32_16x16x32_bf16(al, bh, lg, 0, 0, 0);
            lg = __builtin_amdgcn_mfma_f32_16x16x32_bf16(ah, bl, lg, 0, 0, 0);
        }

        // softmax over k: 16 lanes of a quad-group hold the 16 cols of a row
        #pragma unroll
        for (int r = 0; r < 4; ++r) {
            float v  = lg[r];
            float mx = v;
            mx = fmaxf(mx, __shfl_xor(mx, 1));
            mx = fmaxf(mx, __shfl_xor(mx, 2));
            mx = fmaxf(mx, __shfl_xor(mx, 4));
            mx = fmaxf(mx, __shfl_xor(mx, 8));
            float e = __expf(v - mx);
            float s = e;
            s += __shfl_xor(s, 1);
            s += __shfl_xor(s, 2);
            s += __shfl_xor(s, 4);
            s += __shfl_xor(s, 8);
            int grow = (int)r0 + w * 16 + quad * 4 + r;
            int mv   = mask[grow];
            float ov = mv ? (e / s) * 0.25f : -2500.0f;   // (-10000)/sqrt(16)
            P[(long)grow * KDIM + l15] = ov;
        }
    }
}

// ---------------------------------------------------------------------------
// Kernel 2: per-b. Phase 1: softmax over S of P[b] (exp(-2500)==0 handles
// the mask) * time_f_w -> wl in LDS. Phase 2: wave (sh,hh) covers s-half sh,
// h-half hh: lane owns 2 h-cols, so X is read exactly once and each set of
// 4 ds_read_b128 D-reads feeds 32 FMAs. Cross-wave s-reduce via LDS.
// ---------------------------------------------------------------------------
__global__ __launch_bounds__(256) void softs_agg_kernel(
    const float* __restrict__ X, const float* __restrict__ tf,
    const float* __restrict__ P, float* __restrict__ out)
{
    __shared__ float wl[SDIM * KDIM];        // 12.8 KB
    __shared__ float tfl[SDIM];
    __shared__ float psum[256];
    __shared__ float invk[KDIM];
    __shared__ float red[KDIM * HDIM];       // 16 KB: partials from s-half 1

    const int tid = threadIdx.x;
    const int b   = blockIdx.x;

    const float* Pb = P + (long)b * SDIM * KDIM;
    float ps = 0.f;
    #pragma unroll
    for (int t = 0; t < 13; ++t) {
        int i = tid + t * 256;
        if (i < SDIM * KDIM) {
            float e = __expf(Pb[i]);
            wl[i] = e;
            ps += e;
        }
    }
    psum[tid] = ps;
    if (tid < SDIM) tfl[tid] = tf[b * SDIM + tid];
    __syncthreads();

    if (tid < KDIM) {
        float s = 0.f;
        #pragma unroll
        for (int g = 0; g < 16; ++g) s += psum[tid + g * 16];
        invk[tid] = 1.f / s;
    }
    __syncthreads();

    #pragma unroll
    for (int t = 0; t < 13; ++t) {
        int i = tid + t * 256;
        if (i < SDIM * KDIM) wl[i] *= tfl[i >> 4] * invk[i & 15];
    }
    __syncthreads();

    const int wv = tid >> 6;
    const int sh = wv >> 1;      // s-half: [100*sh, 100*sh+100)
    const int hh = wv & 1;       // h-half: cols 128*hh..128*hh+127
    const int ln = tid & 63;     // lane -> 2 h-cols: 128*hh + 2*ln

    float accx[KDIM], accy[KDIM];
    #pragma unroll
    for (int k = 0; k < KDIM; ++k) { accx[k] = 0.f; accy[k] = 0.f; }

    const float2* Xb  = (const float2*)(X + (long)b * SDIM * HDIM) + hh * 64 + ln;
    const f32x4*  wl4 = (const f32x4*)wl;
    const int s0 = sh * 100;
    #pragma unroll 4
    for (int si = 0; si < 100; ++si) {
        int s = s0 + si;
        float2 x = Xb[(long)s * (HDIM / 2)];   // coalesced 512B per wave
        f32x4 d0 = wl4[s * 4 + 0];             // wave-uniform LDS b128
        f32x4 d1 = wl4[s * 4 + 1];
        f32x4 d2 = wl4[s * 4 + 2];
        f32x4 d3 = wl4[s * 4 + 3];
        #pragma unroll
        for (int j = 0; j < 4; ++j) {
            accx[0 + j]  = fmaf(x.x, d0[j], accx[0 + j]);
            accx[4 + j]  = fmaf(x.x, d1[j], accx[4 + j]);
            accx[8 + j]  = fmaf(x.x, d2[j], accx[8 + j]);
            accx[12 + j] = fmaf(x.x, d3[j], accx[12 + j]);
            accy[0 + j]  = fmaf(x.y, d0[j], accy[0 + j]);
            accy[4 + j]  = fmaf(x.y, d1[j], accy[4 + j]);
            accy[8 + j]  = fmaf(x.y, d2[j], accy[8 + j]);
            accy[12 + j] = fmaf(x.y, d3[j], accy[12 + j]);
        }
    }

    // s-half 1 waves deposit partials; s-half 0 waves add and store.
    if (sh == 1) {
        #pragma unroll
        for (int k = 0; k < KDIM; ++k) {
            red[k * HDIM + hh * 128 + 2 * ln + 0] = accx[k];
            red[k * HDIM + hh * 128 + 2 * ln + 1] = accy[k];
        }
    }
    __syncthreads();
    if (sh == 0) {
        float* ob = out + (long)b * KDIM * HDIM + hh * 128 + 2 * ln;
        #pragma unroll
        for (int k = 0; k < KDIM; ++k) {
            float2 o;
            o.x = accx[k] + red[k * HDIM + hh * 128 + 2 * ln + 0];
            o.y = accy[k] + red[k * HDIM + hh * 128 + 2 * ln + 1];
            *(float2*)(ob + (long)k * HDIM) = o;
        }
    }
}

extern "C" void kernel_launch(void* const* d_in, const int* in_sizes, int n_in,
                              void* d_out, int out_size, void* d_ws, size_t ws_size,
                              hipStream_t stream) {
    (void)in_sizes; (void)n_in; (void)out_size; (void)ws_size;
    const float* X    = (const float*)d_in[0];
    const int*   mask = (const int*)  d_in[1];
    const float* tf   = (const float*)d_in[2];
    const float* W1   = (const float*)d_in[3];
    const float* b1   = (const float*)d_in[4];
    const float* W2   = (const float*)d_in[5];
    const float* b2   = (const float*)d_in[6];
    const float* W3   = (const float*)d_in[7];
    float* out = (float*)d_out;

    char* ws = (char*)d_ws;
    float*  P   = (float*)ws;                          // 102400*16*4 = 6,553,600 B
    __bf16* w1h = (__bf16*)(ws + 6553600);             // 65536 elems each
    __bf16* w1l = w1h + 65536;
    __bf16* w2h = w1l + 65536;
    __bf16* w2l = w2h + 65536;
    __bf16* w3h = w2l + 65536;                         // 4096 elems each
    __bf16* w3l = w3h + 4096;

    pack_w_kernel<<<256, 256, 0, stream>>>(W1, w1h, w1l, 8);
    pack_w_kernel<<<256, 256, 0, stream>>>(W2, w2h, w2l, 8);
    pack_w_kernel<<<16,  256, 0, stream>>>(W3, w3h, w3l, 4);
    mlp_softk_mfma<<<NROWS / TM, 256, 0, stream>>>(X, mask, w1h, w1l, b1,
                                                   w2h, w2l, b2, w3h, w3l, P);
    softs_agg_kernel<<<BDIM, 256, 0, stream>>>(X, tf, P, out);
}